// Round 10
// baseline (735.814 us; speedup 1.0000x reference)
//
#include <hip/hip_runtime.h>
#include <stdint.h>
#include <math.h>

// Problem constants (from reference):
#define BB 8
#define CC 32
#define TT 3136      // 56*56
#define TTP 3328     // padded to 13*256 (pad rows zeroed, masked)
#define KK 9
#define OC 64

#define NEGINF (-3.0e38f)
#define BR 16        // rows per block
#define RT 4         // rows per thread (per scanner)
#define MM 4         // col accumulators per thread
#define BC 256       // cols per LDS tile
#define NTILE 13     // TTP / BC
#define CAP 64       // candidate cap per row
#define EPS 1e-4f    // >= 100x fp32-vs-fp64 dot error; validated R5..R9

__device__ __forceinline__ uint32_t f2s(float v) {
    uint32_t u = __float_as_uint(v);
    return (u & 0x80000000u) ? ~u : (u | 0x80000000u);
}
__device__ __forceinline__ float s2f(uint32_t u) {
    u = (u & 0x80000000u) ? (u & 0x7FFFFFFFu) : ~u;
    return __uint_as_float(u);
}

// ---------------------------------------------------------------------------
// Kernel 1: transposed copies + norms; zero-fills xnT pad rows [TT, TTP).
// ---------------------------------------------------------------------------
__global__ __launch_bounds__(256) void norm_kernel(
    const float* __restrict__ x, float* __restrict__ xnT,
    float* __restrict__ xfT, double* __restrict__ invn)
{
    int t = blockIdx.x * 256 + threadIdx.x;
    int b = blockIdx.y;
    if (t >= TTP) return;
    float* pn = xnT + ((size_t)b * TTP + t) * CC;
    if (t >= TT) {
#pragma unroll
        for (int c = 0; c < CC; c += 4)
            *(float4*)(pn + c) = make_float4(0.f, 0.f, 0.f, 0.f);
        return;
    }
    const float* xp = x + (size_t)b * CC * TT + t;
    float v[CC];
    double ss = 0.0;
#pragma unroll
    for (int c = 0; c < CC; ++c) {
        v[c] = xp[(size_t)c * TT];
        ss = fma((double)v[c], (double)v[c], ss);
    }
    double inv = 1.0 / fmax(sqrt(ss), 1e-12);
    invn[(size_t)b * TT + t] = inv;
    float invf = (float)inv;
    float* pf = xfT + ((size_t)b * TT + t) * CC;
#pragma unroll
    for (int c = 0; c < CC; c += 4) {
        *(float4*)(pf + c) = make_float4(v[c], v[c+1], v[c+2], v[c+3]);
        *(float4*)(pn + c) = make_float4(v[c]*invf, v[c+1]*invf, v[c+2]*invf, v[c+3]*invf);
    }
}

// ---------------------------------------------------------------------------
// Staging: thread tid owns column (ct0+tid); 2 chunks of 4 float4 with a
// sched_barrier after each -> <=16 staging regs, no cross-tile pipelining.
// colbufT layout: [cq=8][col=256] float4; wave reads/writes are contiguous
// 1KB per instruction (LDS bandwidth floor, no pathological conflicts).
// ---------------------------------------------------------------------------
#define STAGE_TILE(dst, src, bpad, ct0)                                        \
    {                                                                          \
        const float4* gp = (const float4*)&(src)[((bpad) + (ct0) + tid) * CC]; \
        _Pragma("unroll")                                                      \
        for (int ch = 0; ch < 2; ++ch) {                                       \
            float4 s0 = gp[ch*4+0], s1 = gp[ch*4+1],                           \
                   s2 = gp[ch*4+2], s3 = gp[ch*4+3];                           \
            (dst)[(ch*4+0)*256 + tid] = s0;                                    \
            (dst)[(ch*4+1)*256 + tid] = s1;                                    \
            (dst)[(ch*4+2)*256 + tid] = s2;                                    \
            (dst)[(ch*4+3)*256 + tid] = s3;                                    \
            __builtin_amdgcn_sched_barrier(0);                                 \
        }                                                                      \
    }

// Tile GEMM: RT=4 rows x MM=4 cols per thread; one sched_barrier per cq
// bounds the live set (acc 16 + bv 16 + a<=16). Chain order per (r,m) is
// identical to R5..R9 -> bit-identical fp32 scores.
#define TILE_GEMM(accvar)                                                      \
    {                                                                          \
        _Pragma("unroll")                                                      \
        for (int r = 0; r < RT; ++r)                                           \
            _Pragma("unroll")                                                  \
            for (int m = 0; m < MM; ++m) accvar[r][m] = 0.f;                   \
        _Pragma("unroll")                                                      \
        for (int cq = 0; cq < 8; ++cq) {                                       \
            float4 bv[MM];                                                     \
            _Pragma("unroll")                                                  \
            for (int m = 0; m < MM; ++m)                                       \
                bv[m] = colbufT[cq * 256 + j + 64 * m];                        \
            _Pragma("unroll")                                                  \
            for (int r = 0; r < RT; ++r) {                                     \
                float4 a = *(const float4*)&rowbuf[(ig * RT + r) * CC + cq*4]; \
                _Pragma("unroll")                                              \
                for (int m = 0; m < MM; ++m) {                                 \
                    accvar[r][m] = fmaf(a.x, bv[m].x, accvar[r][m]);           \
                    accvar[r][m] = fmaf(a.y, bv[m].y, accvar[r][m]);           \
                    accvar[r][m] = fmaf(a.z, bv[m].z, accvar[r][m]);           \
                    accvar[r][m] = fmaf(a.w, bv[m].w, accvar[r][m]);           \
                }                                                              \
            }                                                                  \
            __builtin_amdgcn_sched_barrier(0);                                 \
        }                                                                      \
    }

// ---------------------------------------------------------------------------
// Kernel 2a: pass A — per-thread row maxima over 52 disjoint cols;
// theta[row] = 9th-largest of 64 per-lane maxima - EPS.
// Block: 256 thr = 4 row-groups(ig, RT=4 rows) x 64 scanners(j). BR=16.
// ---------------------------------------------------------------------------
__global__ __launch_bounds__(256) void topk_a(
    const float* __restrict__ xnT, float* __restrict__ thbuf)
{
    __shared__ __align__(16) float4 colbufT[8 * 256];   // 32 KB
    __shared__ __align__(16) float  rowbuf[BR * CC];    // 2 KB

    int tid   = threadIdx.x;
    int b     = blockIdx.y;
    int browg = blockIdx.x * BR;
    size_t bpad = (size_t)b * TTP;

    int ig = tid >> 6;
    int j  = tid & 63;

    if (tid < BR * 8) {   // stage 16 row vectors
        int row = tid >> 3, part = tid & 7;
        *(float4*)&rowbuf[row * CC + part * 4] =
            *(const float4*)&xnT[(bpad + browg + row) * CC + part * 4];
    }

    float mseg[RT];
#pragma unroll
    for (int r = 0; r < RT; ++r) mseg[r] = NEGINF;

    for (int tt = 0; tt < NTILE; ++tt) {
        int ct0 = tt * BC;
        __syncthreads();
        __builtin_amdgcn_sched_barrier(0);
        STAGE_TILE(colbufT, xnT, bpad, ct0);
        __syncthreads();
        __builtin_amdgcn_sched_barrier(0);

        float acc[RT][MM];
        TILE_GEMM(acc);

        int realm = (TT - ct0) >> 6;    // >=4 for full tiles, 1 on last real
#pragma unroll
        for (int r = 0; r < RT; ++r) {
            unsigned rel = (unsigned)(browg + ig*RT + r - ct0);
#pragma unroll
            for (int m = 0; m < MM; ++m) {
                float v = ((unsigned)(j + 64*m) == rel) ? NEGINF : acc[r][m];
                if (m < realm) mseg[r] = fmaxf(mseg[r], v);
            }
        }
    }

    // theta: 9th-largest of 64 per-lane maxima (validated R6..R9)
#pragma unroll
    for (int r = 0; r < RT; ++r) {
        uint32_t key = f2s(mseg[r]);
        uint32_t nth = 0;
        for (int round = 0; round < 9; ++round) {
            uint32_t m = key;
#pragma unroll
            for (int d = 1; d < 64; d <<= 1) {
                uint32_t o = (uint32_t)__shfl_xor((int)m, d, 64);
                m = (o > m) ? o : m;
            }
            nth = m;
            unsigned long long bal = __ballot(key == m);
            int leader = __ffsll(bal) - 1;
            if (j == leader) key = 0;
        }
        if (j == 0)
            thbuf[(size_t)b * TT + browg + ig*RT + r] = s2f(nth) - EPS;
    }
}

// ---------------------------------------------------------------------------
// Kernel 2b: pass B — recompute (bit-identical), collect cols >= theta;
// pass C — fp64 exact re-rank -> top-8 + self, sorted ascending.
// ---------------------------------------------------------------------------
__global__ __launch_bounds__(256) void topk_b(
    const float* __restrict__ xnT, const float* __restrict__ xfT,
    const double* __restrict__ invn, const float* __restrict__ thbuf,
    int* __restrict__ idxo)
{
    __shared__ __align__(16) float4 colbufT[8 * 256];   // 32 KB (pass C: scorebuf)
    __shared__ __align__(16) float  rowbuf[BR * CC];    // 2 KB
    __shared__ uint16_t candidx[BR * CAP];              // 2 KB
    __shared__ int cnt[BR];

    int tid   = threadIdx.x;
    int b     = blockIdx.y;
    int browg = blockIdx.x * BR;
    size_t bpad  = (size_t)b * TTP;
    size_t bbase = (size_t)b * TT;

    int ig = tid >> 6;
    int j  = tid & 63;

    if (tid < BR * 8) {
        int row = tid >> 3, part = tid & 7;
        *(float4*)&rowbuf[row * CC + part * 4] =
            *(const float4*)&xnT[(bpad + browg + row) * CC + part * 4];
    }
    if (tid < BR) cnt[tid] = 0;

    float th[RT];
#pragma unroll
    for (int r = 0; r < RT; ++r)
        th[r] = thbuf[bbase + browg + ig*RT + r];

    for (int tt = 0; tt < NTILE; ++tt) {
        int ct0 = tt * BC;
        __syncthreads();
        __builtin_amdgcn_sched_barrier(0);
        STAGE_TILE(colbufT, xnT, bpad, ct0);
        __syncthreads();
        __builtin_amdgcn_sched_barrier(0);

        float acc[RT][MM];
        TILE_GEMM(acc);

        int realm = (TT - ct0) >> 6;
#pragma unroll
        for (int r = 0; r < RT; ++r) {
            int rowl = ig*RT + r;
            unsigned rel = (unsigned)(browg + rowl - ct0);
#pragma unroll
            for (int m = 0; m < MM; ++m) {
                float v = ((unsigned)(j + 64*m) == rel) ? NEGINF : acc[r][m];
                if (m < realm && v >= th[r]) {
                    int n = atomicAdd(&cnt[rowl], 1);
                    if (n < CAP) candidx[rowl * CAP + n] = (uint16_t)(ct0 + j + 64*m);
                }
            }
        }
    }
    __syncthreads();

    // ---------------- pass C: fp64 exact re-rank (validated R2..R9) --------
    double* scorebuf = (double*)colbufT;   // 16*64*8 = 8 KB <= 32 KB
    for (int g = tid; g < BR * CAP; g += 256) {
        int row  = g >> 6;             // CAP = 64
        int slot = g & 63;
        int n = min(cnt[row], CAP);
        if (slot < n) {
            int s = (int)candidx[row * CAP + slot];
            const float* xt = xfT + (bbase + browg + row) * CC;
            const float* xs = xfT + (bbase + s) * CC;
            double a2 = 0.0;
#pragma unroll
            for (int c = 0; c < CC; c += 4) {
                float4 xtv = *(const float4*)(xt + c);
                float4 xsv = *(const float4*)(xs + c);
                a2 = fma((double)xtv.x, (double)xsv.x, a2);
                a2 = fma((double)xtv.y, (double)xsv.y, a2);
                a2 = fma((double)xtv.z, (double)xsv.z, a2);
                a2 = fma((double)xtv.w, (double)xsv.w, a2);
            }
            scorebuf[row * CAP + slot] = a2 * invn[bbase + s];
        }
    }
    __syncthreads();

    if ((tid & 15) == 0) {
        int row = tid >> 4;            // 0..15
        int t   = browg + row;
        int n   = min(cnt[row], CAP);
        double v8[8]; int i8[8];
#pragma unroll
        for (int jj = 0; jj < 8; ++jj) { v8[jj] = -1.0e300; i8[jj] = 0x7FFFFFFF; }
        for (int sl = 0; sl < n; ++sl) {
            double scr = scorebuf[row * CAP + sl];
            int    idx = (int)candidx[row * CAP + sl];
            bool better7 = (scr > v8[7]) || (scr == v8[7] && idx < i8[7]);
            if (better7) {
#pragma unroll
                for (int jj = 7; jj >= 1; --jj) {
                    bool up   = (scr > v8[jj-1]) || (scr == v8[jj-1] && idx < i8[jj-1]);
                    bool here = ((scr > v8[jj]) || (scr == v8[jj] && idx < i8[jj])) && !up;
                    v8[jj] = up ? v8[jj-1] : (here ? scr : v8[jj]);
                    i8[jj] = up ? i8[jj-1] : (here ? idx : i8[jj]);
                }
                bool top = (scr > v8[0]) || (scr == v8[0] && idx < i8[0]);
                if (top) { v8[0] = scr; i8[0] = idx; }
            }
        }
        int oi[9];
#pragma unroll
        for (int jj = 0; jj < 8; ++jj)
            oi[jj] = (i8[jj] == 0x7FFFFFFF) ? t : i8[jj];   // safety, never fires
        oi[8] = t;   // self (sim forced 1.1 -> always top-1)
        for (int a = 1; a < 9; ++a) {
            int kv = oi[a]; int jj = a - 1;
            while (jj >= 0 && oi[jj] > kv) { oi[jj+1] = oi[jj]; --jj; }
            oi[jj+1] = kv;
        }
        int* op = idxo + (bbase + t) * KK;
#pragma unroll
        for (int m = 0; m < 9; ++m) op[m] = oi[m];
    }
}

// ---------------------------------------------------------------------------
// Kernel 3: gather + conv1d(kernel=K, stride=K).  (validated R9)
// ---------------------------------------------------------------------------
__global__ __launch_bounds__(256) void gconv_kernel(
    const float* __restrict__ xfT, const int* __restrict__ idxi,
    const float* __restrict__ Wt, float* __restrict__ out)
{
    __shared__ float4 wl[KK * 8 * 64];   // 73.7 KB: [k][c4][o]

    int tid = threadIdx.x;
    int b   = blockIdx.y;
    int t0  = blockIdx.x * 64;
    size_t bbase = (size_t)b * TT;

    for (int f = tid; f < OC * 288; f += 256) {
        int o  = f / 288;
        int ck = f - o * 288;
        int c  = ck / KK;
        int k  = ck - c * KK;
        ((float*)wl)[(((k*8 + (c >> 2)) * 64 + o) << 2) + (c & 3)] = Wt[f];
    }
    __syncthreads();

    int w    = tid >> 6;
    int lane = tid & 63;        // = output channel o
    int tw0  = t0 + w * 16;

    float res[16];

    for (int i0 = 0; i0 < 16; i0 += 2) {
        float aa[2][4];
#pragma unroll
        for (int i = 0; i < 2; ++i)
#pragma unroll
            for (int q = 0; q < 4; ++q) aa[i][q] = 0.f;

        const int* ipa = idxi + (bbase + tw0 + i0) * KK;
        const int* ipb = ipa + KK;
#pragma unroll 2
        for (int k = 0; k < KK; ++k) {
            int sa = __builtin_amdgcn_readfirstlane(ipa[k]);
            int sb = __builtin_amdgcn_readfirstlane(ipb[k]);
            const float* ca = xfT + (bbase + sa) * CC;
            const float* cb = xfT + (bbase + sb) * CC;
#pragma unroll
            for (int c4 = 0; c4 < 8; ++c4) {
                float4 wv = wl[(k*8 + c4) * 64 + lane];
                int q = c4 & 3;
                float4 xa = *(const float4*)(ca + c4*4);
                aa[0][q] = fmaf(xa.x, wv.x, aa[0][q]); aa[0][q] = fmaf(xa.y, wv.y, aa[0][q]);
                aa[0][q] = fmaf(xa.z, wv.z, aa[0][q]); aa[0][q] = fmaf(xa.w, wv.w, aa[0][q]);
                float4 xb = *(const float4*)(cb + c4*4);
                aa[1][q] = fmaf(xb.x, wv.x, aa[1][q]); aa[1][q] = fmaf(xb.y, wv.y, aa[1][q]);
                aa[1][q] = fmaf(xb.z, wv.z, aa[1][q]); aa[1][q] = fmaf(xb.w, wv.w, aa[1][q]);
            }
            __builtin_amdgcn_sched_barrier(0);
        }
        res[i0]     = (aa[0][0] + aa[0][1]) + (aa[0][2] + aa[0][3]);
        res[i0 + 1] = (aa[1][0] + aa[1][1]) + (aa[1][2] + aa[1][3]);
    }

    float* op = out + ((size_t)b * OC + lane) * TT + tw0;
#pragma unroll
    for (int p = 0; p < 4; ++p)
        *(float4*)(op + p*4) = make_float4(res[p*4], res[p*4+1], res[p*4+2], res[p*4+3]);
}

// ---------------------------------------------------------------------------
extern "C" void kernel_launch(void* const* d_in, const int* in_sizes, int n_in,
                              void* d_out, int out_size, void* d_ws, size_t ws_size,
                              hipStream_t stream)
{
    const float* x  = (const float*)d_in[0];   // [8][32][56][56]
    const float* Wt = (const float*)d_in[1];   // [64][32][9]
    float* out = (float*)d_out;                // [8][64][56][56]

    // workspace: xnT (fp32, padded TTP) | xfT (fp32) | invn (fp64) | idx | thbuf
    float*  xnT  = (float*)d_ws;
    float*  xfT  = xnT + (size_t)BB * TTP * CC;
    double* invn = (double*)(xfT + (size_t)BB * TT * CC);
    int*    idw  = (int*)(invn + (size_t)BB * TT);
    float*  thb  = (float*)(idw + (size_t)BB * TT * KK);

    dim3 g1((TTP + 255) / 256, BB);
    norm_kernel<<<g1, 256, 0, stream>>>(x, xnT, xfT, invn);

    dim3 g2(TT / BR, BB);    // 196 x 8 = 1568 blocks
    topk_a<<<g2, 256, 0, stream>>>(xnT, thb);
    topk_b<<<g2, 256, 0, stream>>>(xnT, xfT, invn, thb, idw);

    dim3 g3(TT / 64, BB);    // 49 x 8 = 392 blocks
    gconv_kernel<<<g3, 256, 0, stream>>>(xfT, idw, Wt, out);
}